// Round 5
// baseline (88.396 us; speedup 1.0000x reference)
//
#include <hip/hip_runtime.h>
#include <math.h>

// Tropical min-max matmul: out[b,o] = min_i max(x[b,i], w[i,o])
// B=1024, I=512, O=512, fp32.
//
// Round 5:
//  - part: 128x128 tile, 256 thr, 8x8 outputs/thread, split-K=16 (32 k/block).
//    Grid (4,8,16) = 512 blocks = 2 blocks/CU = 2 waves/SIMD.
//    Pipe model per wave per k4: 192 VALU insts (384 SIMD-cyc) vs 16 b128
//    LDS reads; per CU (8 waves): LDS 12 b128-equiv*8*12cyc ~ VALU -> 1:1
//    balanced, ~5.1us floor with TLP latency hiding.
//  - XCD locality: z slowest, xy-count=32 (multiple of 8) => under %8
//    round-robin dispatch, XCD = (x+4y)%8 independent of z: all 16 k-slices
//    of a tile are produced on ONE XCD. Reduce uses the same (x,y) grid =>
//    reads its 32MB of partials from the local L2, not cross-XCD snoops
//    (R2-R4's hidden ~25us cost). Heuristic affects speed only.
//  - min3 fusion: acc = min3(acc, max(x0,w0), max(x1,w1)) = 1.5 inst/update.

#define XS_STRIDE 36

__device__ __forceinline__ float4 vmax4(float s, float4 v) {
    return make_float4(fmaxf(s, v.x), fmaxf(s, v.y), fmaxf(s, v.z), fmaxf(s, v.w));
}
__device__ __forceinline__ float4 vmin3(float4 a, float4 b, float4 c) {
    // fmin(fmin(a,b),c) -> v_min3_f32
    return make_float4(fminf(fminf(a.x, b.x), c.x),
                       fminf(fminf(a.y, b.y), c.y),
                       fminf(fminf(a.z, b.z), c.z),
                       fminf(fminf(a.w, b.w), c.w));
}

__global__ __launch_bounds__(256, 2) void minmax_part(
    const float* __restrict__ x,    // [1024, 512]
    const float* __restrict__ w,    // [512, 512]
    float* __restrict__ dst,        // partial slices (or out when gridDim.z==1)
    int nslab)                      // k-slabs of 32 per block
{
    __shared__ float xs[128 * XS_STRIDE];   // 18432 B
    __shared__ float ws[32 * 128];          // 16384 B

    const int t  = threadIdx.x;
    const int tx = t & 15;          // cols tx*4..+3 and 64+tx*4..+3
    const int ty = t >> 4;          // rows ty+16r, r=0..7

    const int o0 = blockIdx.x * 128;
    const int b0 = blockIdx.y * 128;
    const int kbase = blockIdx.z * nslab * 32;

    float4 acc[8][2];
#pragma unroll
    for (int r = 0; r < 8; ++r)
#pragma unroll
        for (int g = 0; g < 2; ++g)
            acc[r][g] = make_float4(INFINITY, INFINITY, INFINITY, INFINITY);

    for (int s = 0; s < nslab; ++s) {
        const int kb = kbase + s * 32;

        __syncthreads();   // protect previous slab's LDS reads
        // stage x tile [128 rows][32 k]: 4 float4/thread, coalesced
#pragma unroll
        for (int i = 0; i < 4; ++i) {
            const int f = i * 256 + t;
            const int row = f >> 3, c4 = (f & 7) * 4;
            *(float4*)(xs + row * XS_STRIDE + c4) =
                *(const float4*)(x + (size_t)(b0 + row) * 512 + kb + c4);
        }
        // stage w tile [32 k][128 cols]: 4 float4/thread, coalesced
#pragma unroll
        for (int i = 0; i < 4; ++i) {
            const int f = i * 256 + t;
            const int k = f >> 5, c4 = (f & 31) * 4;
            *(float4*)(ws + k * 128 + c4) =
                *(const float4*)(w + (size_t)(kb + k) * 512 + o0 + c4);
        }
        __syncthreads();

#pragma unroll
        for (int k4 = 0; k4 < 8; ++k4) {
            float4 xf[8];
#pragma unroll
            for (int r = 0; r < 8; ++r)
                xf[r] = *(const float4*)(xs + (ty + 16 * r) * XS_STRIDE + 4 * k4);
            float4 wf[4][2];
#pragma unroll
            for (int j = 0; j < 4; ++j)
#pragma unroll
                for (int g = 0; g < 2; ++g)
                    wf[j][g] = *(const float4*)(ws + (4 * k4 + j) * 128 + tx * 4 + 64 * g);
#pragma unroll
            for (int r = 0; r < 8; ++r) {
#pragma unroll
                for (int g = 0; g < 2; ++g) {
                    float4 a = acc[r][g];
                    a = vmin3(a, vmax4(xf[r].x, wf[0][g]), vmax4(xf[r].y, wf[1][g]));
                    a = vmin3(a, vmax4(xf[r].z, wf[2][g]), vmax4(xf[r].w, wf[3][g]));
                    acc[r][g] = a;
                }
            }
        }
    }

    float* outp = dst + (size_t)blockIdx.z * (1024 * 512);
#pragma unroll
    for (int r = 0; r < 8; ++r)
#pragma unroll
        for (int g = 0; g < 2; ++g)
            *(float4*)(outp + (size_t)(b0 + ty + 16 * r) * 512 + o0 + tx * 4 + 64 * g) = acc[r][g];
}

// grid (4,8,16): block (x,y,u) reduces rows u*8..u*8+7 of tile (x,y).
// Same (x,y) => same XCD as the producer blocks (z-slowest, 32 xy-tiles).
__global__ __launch_bounds__(256) void minmax_reduce(
    const float* __restrict__ part, float* __restrict__ out)
{
    const int t   = threadIdx.x;
    const int o0  = blockIdx.x * 128;
    const int b0  = blockIdx.y * 128;
    const int row = blockIdx.z * 8 + (t >> 5);
    const int c4  = (t & 31) * 4;

    const size_t idx = ((size_t)(b0 + row) * 512 + o0 + c4) >> 2;  // float4 index
    const float4* p = (const float4*)part;

    float4 v = p[idx];
#pragma unroll
    for (int s = 1; s < 16; ++s) {
        const float4 u = p[idx + (size_t)s * 131072];
        v.x = fminf(v.x, u.x);
        v.y = fminf(v.y, u.y);
        v.z = fminf(v.z, u.z);
        v.w = fminf(v.w, u.w);
    }
    ((float4*)out)[idx] = v;
}

extern "C" void kernel_launch(void* const* d_in, const int* in_sizes, int n_in,
                              void* d_out, int out_size, void* d_ws, size_t ws_size,
                              hipStream_t stream) {
    const float* x = (const float*)d_in[0];   // [1024, 512]
    const float* w = (const float*)d_in[1];   // [512, 512]
    float* out = (float*)d_out;               // [1024, 512]

    const size_t need = 16ull * 1024 * 512 * 4;   // 32 MB of partials
    if (ws_size >= need) {
        minmax_part<<<dim3(4, 8, 16), 256, 0, stream>>>(x, w, (float*)d_ws, 1);
        minmax_reduce<<<dim3(4, 8, 16), 256, 0, stream>>>((const float*)d_ws, out);
    } else {
        // fallback: no split-K, write out directly (correct, slower)
        minmax_part<<<dim3(4, 8, 1), 256, 0, stream>>>(x, w, out, 16);
    }
}